// Round 5
// baseline (528.543 us; speedup 1.0000x reference)
//
#include <hip/hip_runtime.h>
#include <cmath>

#define BATCH 1024

// ---------------- Fused Level 0 + Level 1, 8-row stripes, high occupancy ----------------
__global__ __launch_bounds__(256, 8) void k_L01(
    const float* __restrict__ u, const float* __restrict__ f, const float* __restrict__ a,
    const float* __restrict__ c0w, const float* __restrict__ c0b,
    const float* __restrict__ c1w, const float* __restrict__ c1b,
    const float* __restrict__ r1w, const float* __restrict__ r3w,
    float* __restrict__ out_us0, float* __restrict__ out_diva0,
    float* __restrict__ out_f, float* __restrict__ out_a,
    float* __restrict__ out_diva1,
    float* __restrict__ ws_a1, float* __restrict__ ws_r1, float* __restrict__ ws_us1)
{
    const int b = blockIdx.y;
    const int bx = blockIdx.x;      // 0..15
    const int Y0 = bx * 8;          // level-0 row base
    const int y0 = bx * 4;          // level-1 row base
    const int tid = threadIdx.x;
    const int tx = tid & 127, ty = tid >> 7;

    __shared__ float asrc[14][128];  // a rows Y0-2 .. Y0+11 (clamped)
    __shared__ float td0[10][128];   // tanh(diva0) rows Y0-1 .. Y0+8 (valid only)
    __shared__ float r0s[9][128];    // r0 rows Y0 .. Y0+8 (valid only)
    __shared__ float a1s[7][68];     // a1 rows y0-1..y0+5 (clamped), cols -1..64 (clamped)
    __shared__ float td1[6][64];     // tanh(diva1) rows y0-1..y0+4 (valid), cols 0..62

    // ---- A: stage a rows (float4, fully coalesced) ----
    {
        const float4* ab4 = reinterpret_cast<const float4*>(a + (size_t)b * 16384);
        float4* s4 = reinterpret_cast<float4*>(&asrc[0][0]);
        const int c4 = tid & 31, r4 = tid >> 5;
        #pragma unroll
        for (int r = r4; r < 14; r += 8) {
            int g = Y0 - 2 + r; g = g < 0 ? 0 : (g > 127 ? 127 : g);
            s4[r * 32 + c4] = ab4[g * 32 + c4];
        }
    }

    // ---- prefetch u/f for phase C (issued alongside the staging loads;
    //      values live in registers across the barrier) ----
    const size_t rowbase = (size_t)b * 16129;
    float ur[5], fr[5];
    #pragma unroll
    for (int k = 0; k < 5; k++) {
        int rr = ty + 2 * k;
        int g = Y0 + rr;
        if (rr < 9 && g <= 126 && tx < 127) {
            size_t idx = rowbase + (size_t)g * 127 + tx;
            ur[k] = u[idx];
            fr[k] = f[idx];
        }
    }
    __syncthreads();

    const float w00 = c1w[0], w01 = c1w[1], w10 = c1w[2], w11 = c1w[3], b1 = c1b[0];

    // ---- B: td0 rows Y0-1..Y0+8 ----
    #pragma unroll
    for (int r = ty; r < 10; r += 2) {
        int g = Y0 - 1 + r;
        if (g >= 0 && g <= 126 && tx < 127) {
            float d = asrc[r + 1][tx] * w00 + asrc[r + 1][tx + 1] * w01
                    + asrc[r + 2][tx] * w10 + asrc[r + 2][tx + 1] * w11 + b1;
            td0[r][tx] = tanhf(d);
        }
    }
    // ---- P: a passthrough rows Y0..Y0+7 (float4) ----
    {
        float4* oa4 = reinterpret_cast<float4*>(out_a + (size_t)b * 16384);
        const float4* s4 = reinterpret_cast<const float4*>(&asrc[0][0]);
        const int c4 = tid & 31, r4 = tid >> 5;
        oa4[(Y0 + r4) * 32 + c4] = s4[(r4 + 2) * 32 + c4];
    }
    // ---- D: a1 restriction (reads asrc only) ----
    const float q00 = r1w[0], q01 = r1w[1], q10 = r1w[2], q11 = r1w[3];
    {
        const int tx2 = tid & 63, ty2 = tid >> 6;
        #pragma unroll
        for (int r = ty2; r < 7; r += 4)
            for (int c = tx2; c < 66; c += 64) {
                int ay = y0 - 1 + r; ay = ay < 0 ? 0 : (ay > 63 ? 63 : ay);
                int ax = c - 1; ax = ax < 0 ? 0 : (ax > 63 ? 63 : ax);
                int la = 2 * ay - (Y0 - 2);
                a1s[r][c] = asrc[la][2 * ax] * q00 + asrc[la][2 * ax + 1] * q01
                          + asrc[la + 1][2 * ax] * q10 + asrc[la + 1][2 * ax + 1] * q11;
            }
    }
    __syncthreads();

    // ---- C: r0s + level-0 outputs (consumes prefetched u/f) ----
    const float c0b0 = c0b[0];
    #pragma unroll
    for (int k = 0; k < 5; k++) {
        int rr = ty + 2 * k;
        if (rr >= 9) break;
        int g = Y0 + rr;
        if (g > 126 || tx >= 127) continue;
        float diva = asrc[rr + 2][tx] * w00 + asrc[rr + 2][tx + 1] * w01
                   + asrc[rr + 3][tx] * w10 + asrc[rr + 3][tx + 1] * w11 + b1;
        size_t idx = rowbase + (size_t)g * 127 + tx;
        float uv = ur[k], fv = fr[k];
        float rv = fv - diva * uv;
        r0s[rr][tx] = rv;
        if (rr < 8) {
            float s = c0b0;
            #pragma unroll
            for (int ky = 0; ky < 3; ky++) {
                int sy = g - 1 + ky; sy = sy < 0 ? 0 : (sy > 126 ? 126 : sy);
                int lr = sy - (Y0 - 1);
                #pragma unroll
                for (int kx = 0; kx < 3; kx++) {
                    int sx = tx - 1 + kx; sx = sx < 0 ? 0 : (sx > 126 ? 126 : sx);
                    s += c0w[ky * 3 + kx] * td0[lr][sx];
                }
            }
            out_diva0[idx] = diva;
            out_us0[idx] = uv + s * rv;
            out_f[idx] = fv;
        }
    }

    // ---- E: a1 out + td1 ----
    const float v00 = c1w[4], v01 = c1w[5], v10 = c1w[6], v11 = c1w[7], b2 = c1b[1];
    {
        const int tx2 = tid & 63, ty2 = tid >> 6;
        ws_a1[(size_t)b * 4096 + (size_t)(y0 + ty2) * 64 + tx2] = a1s[ty2 + 1][tx2 + 1];
        #pragma unroll
        for (int r = ty2; r < 6; r += 4) {
            int dy = y0 - 1 + r;
            if (dy >= 0 && dy <= 62 && tx2 < 63) {
                float d = a1s[r][tx2 + 1] * v00 + a1s[r][tx2 + 2] * v01
                        + a1s[r + 1][tx2 + 1] * v10 + a1s[r + 1][tx2 + 2] * v11 + b2;
                td1[r][tx2] = tanhf(d);
            }
        }
    }
    __syncthreads();

    // ---- F: level-1 outputs rows y0..y0+3 ----
    {
        const int tx2 = tid & 63, ty2 = tid >> 6;
        const int y = y0 + ty2;
        if (y <= 62 && tx2 < 63) {
            float diva = a1s[ty2 + 1][tx2 + 1] * v00 + a1s[ty2 + 1][tx2 + 2] * v01
                       + a1s[ty2 + 2][tx2 + 1] * v10 + a1s[ty2 + 2][tx2 + 2] * v11 + b2;
            float rv = 0.f;
            #pragma unroll
            for (int p = 0; p < 3; p++)
                #pragma unroll
                for (int q = 0; q < 3; q++)
                    rv += r3w[p * 3 + q] * r0s[2 * ty2 + p][2 * tx2 + q];
            float s = c0b[1];
            #pragma unroll
            for (int ky = 0; ky < 3; ky++) {
                int sy = y - 1 + ky; sy = sy < 0 ? 0 : (sy > 62 ? 62 : sy);
                int lr = sy - (y0 - 1);
                #pragma unroll
                for (int kx = 0; kx < 3; kx++) {
                    int sx = tx2 - 1 + kx; sx = sx < 0 ? 0 : (sx > 62 ? 62 : sx);
                    s += c0w[9 + ky * 3 + kx] * td1[lr][sx];
                }
            }
            size_t idx = (size_t)b * 3969 + (size_t)y * 63 + tx2;
            out_diva1[idx] = diva;
            ws_r1[idx] = rv;
            ws_us1[idx] = s * rv;
        }
    }
}

// ---------------- levels 2..4 helper ----------------
template<int N, int NA, int PA, int PD>
__device__ __forceinline__ void level_step(
    const float* ap, const float* rp, float* ac, float* rc, float* us, float* td,
    const float* __restrict__ r1w, const float* __restrict__ r3w,
    const float* __restrict__ c1w, float c1b_,
    const float* __restrict__ c0w, float c0b_,
    float* __restrict__ diva_out, int tid)
{
    const float q00 = r1w[0], q01 = r1w[1], q10 = r1w[2], q11 = r1w[3];
    for (int idx = tid; idx < NA * NA; idx += 256) {
        int y = idx / NA, x = idx % NA;
        const float* p = ap + 2 * y * PA + 2 * x;
        ac[idx] = p[0] * q00 + p[1] * q01 + p[PA] * q10 + p[PA + 1] * q11;
    }
    __syncthreads();
    const float w00 = c1w[0], w01 = c1w[1], w10 = c1w[2], w11 = c1w[3];
    for (int idx = tid; idx < N * N; idx += 256) {
        int y = idx / N, x = idx % N;
        float d = ac[y * NA + x] * w00 + ac[y * NA + x + 1] * w01
                + ac[(y + 1) * NA + x] * w10 + ac[(y + 1) * NA + x + 1] * w11 + c1b_;
        td[idx] = tanhf(d);
        diva_out[idx] = d;
    }
    __syncthreads();
    for (int idx = tid; idx < N * N; idx += 256) {
        int y = idx / N, x = idx % N;
        float rv = 0.f;
        #pragma unroll
        for (int p = 0; p < 3; p++)
            #pragma unroll
            for (int q = 0; q < 3; q++)
                rv += r3w[p * 3 + q] * rp[(2 * y + p) * PD + 2 * x + q];
        float s = c0b_;
        #pragma unroll
        for (int ky = 0; ky < 3; ky++) {
            int sy = y - 1 + ky; sy = sy < 0 ? 0 : (sy > N - 1 ? N - 1 : sy);
            #pragma unroll
            for (int kx = 0; kx < 3; kx++) {
                int sx = x - 1 + kx; sx = sx < 0 ? 0 : (sx > N - 1 ? N - 1 : sx);
                s += c0w[ky * 3 + kx] * td[sy * N + sx];
            }
        }
        rc[idx] = rv;
        us[idx] = s * rv;
    }
    __syncthreads();
}

template<int NO, int NI>
__device__ __forceinline__ void prolong_step(
    float* uo, const float* ui, const float* __restrict__ tw9, int tid)
{
    for (int idx = tid; idx < NO * NO; idx += 256) {
        int y = idx / NO, x = idx % NO;
        float acc = 0.f;
        #pragma unroll
        for (int ky = 0; ky < 3; ky++) {
            int sy = y - ky;
            if (sy & 1) continue;
            int iy = sy >> 1;
            if (iy < 0 || iy >= NI) continue;
            #pragma unroll
            for (int kx = 0; kx < 3; kx++) {
                int sx = x - kx;
                if (sx & 1) continue;
                int ix = sx >> 1;
                if (ix < 0 || ix >= NI) continue;
                acc += tw9[ky * 3 + kx] * ui[iy * NI + ix];
            }
        }
        uo[idx] += acc;
    }
    __syncthreads();
}

// ---------------- Fused: levels 2..4 + prolong 4->3->2->1->0 (one block/image) ----------------
__global__ __launch_bounds__(256) void k_coarse(
    const float* __restrict__ a1, const float* __restrict__ r1,
    const float* __restrict__ us1g, float* __restrict__ us0,
    const float* __restrict__ r1w, const float* __restrict__ r3w,
    const float* __restrict__ c1w, const float* __restrict__ c1b,
    const float* __restrict__ c0w, const float* __restrict__ c0b,
    const float* __restrict__ tw,
    float* __restrict__ diva2, float* __restrict__ diva3, float* __restrict__ diva4)
{
    const int b = blockIdx.x;
    const int tid = threadIdx.x;
    __shared__ float aB[32 * 32];
    __shared__ float rB[31 * 31];
    __shared__ float aC[16 * 16];
    __shared__ float rC[15 * 15];
    __shared__ float aD[8 * 8];
    __shared__ float rD[7 * 7];
    __shared__ float us2s[31 * 31];
    __shared__ float us3s[15 * 15];
    __shared__ float us4s[7 * 7];
    __shared__ float td[31 * 31];
    __shared__ float us1p[63 * 64];   // us1' rows 0..62, stride 64

    // prefetch us1 into registers (latency hides under the level chain)
    const int cx = tid & 63, ry = tid >> 6;
    float us1r[16];
    {
        const float* u1b = us1g + (size_t)b * 3969;
        #pragma unroll
        for (int k = 0; k < 16; k++) {
            int y = ry + 4 * k;
            if (y < 63 && cx < 63) us1r[k] = u1b[y * 63 + cx];
        }
    }

    level_step<31, 32, 64, 63>(a1 + (size_t)b * 4096, r1 + (size_t)b * 3969,
        aB, rB, us2s, td,
        r1w + 4, r3w + 9, c1w + 8, c1b[2], c0w + 18, c0b[2],
        diva2 + (size_t)b * 961, tid);
    level_step<15, 16, 32, 31>(aB, rB, aC, rC, us3s, td,
        r1w + 8, r3w + 18, c1w + 12, c1b[3], c0w + 27, c0b[3],
        diva3 + (size_t)b * 225, tid);
    level_step<7, 8, 16, 15>(aC, rC, aD, rD, us4s, td,
        r1w + 12, r3w + 27, c1w + 16, c1b[4], c0w + 36, c0b[4],
        diva4 + (size_t)b * 49, tid);

    prolong_step<15, 7>(us3s, us4s, tw + 27, tid);
    prolong_step<31, 15>(us2s, us3s, tw + 18, tid);

    // us1' = us1 + convT(us2')  (kept in LDS)
    {
        const float* t1 = tw + 9;
        #pragma unroll
        for (int k = 0; k < 16; k++) {
            int y = ry + 4 * k;
            if (y >= 63 || cx >= 63) continue;
            float acc = us1r[k];
            #pragma unroll
            for (int ky = 0; ky < 3; ky++) {
                int sy = y - ky;
                if ((sy & 1) || sy < 0) continue;
                int iy = sy >> 1;
                if (iy > 30) continue;
                #pragma unroll
                for (int kx = 0; kx < 3; kx++) {
                    int sx = cx - kx;
                    if ((sx & 1) || sx < 0) continue;
                    int ix = sx >> 1;
                    if (ix > 30) continue;
                    acc += t1[ky * 3 + kx] * us2s[iy * 31 + ix];
                }
            }
            us1p[y * 64 + cx] = acc;
        }
    }
    __syncthreads();

    // us0 += convT(us1')
    {
        const float* t0 = tw;
        const int tx = tid & 127, ty = tid >> 7;
        float* o0 = us0 + (size_t)b * 16129;
        if (tx < 127) {
            for (int y = ty; y < 127; y += 2) {
                float acc = 0.f;
                #pragma unroll
                for (int ky = 0; ky < 3; ky++) {
                    int sy = y - ky;
                    if ((sy & 1) || sy < 0) continue;
                    int iy = sy >> 1;
                    if (iy > 62) continue;
                    #pragma unroll
                    for (int kx = 0; kx < 3; kx++) {
                        int sx = tx - kx;
                        if ((sx & 1) || sx < 0) continue;
                        int ix = sx >> 1;
                        if (ix > 62) continue;
                        acc += t0[ky * 3 + kx] * us1p[iy * 64 + ix];
                    }
                }
                o0[(size_t)y * 127 + tx] += acc;
            }
        }
    }
}

extern "C" void kernel_launch(void* const* d_in, const int* in_sizes, int n_in,
                              void* d_out, int out_size, void* d_ws, size_t ws_size,
                              hipStream_t stream) {
    const float* u   = (const float*)d_in[0];
    const float* f   = (const float*)d_in[1];
    const float* a   = (const float*)d_in[2];
    const float* c0w = (const float*)d_in[3];
    const float* c0b = (const float*)d_in[4];
    const float* c1w = (const float*)d_in[5];
    const float* c1b = (const float*)d_in[6];
    const float* r1w = (const float*)d_in[7];
    const float* r3w = (const float*)d_in[8];
    const float* tw  = (const float*)d_in[9];
    float* out = (float*)d_out;
    float* ws  = (float*)d_ws;
    const size_t B = BATCH;

    // d_out layout: us0, f, a, diva0..diva4
    size_t off_us0 = 0;
    size_t off_f   = B * 16129;
    size_t off_a   = off_f + B * 16129;
    size_t off_d0  = off_a + B * 16384;
    size_t off_d1  = off_d0 + B * 16129;
    size_t off_d2  = off_d1 + B * 3969;
    size_t off_d3  = off_d2 + B * 961;
    size_t off_d4  = off_d3 + B * 225;

    // ws layout: a1, r1, us1
    size_t w_a1  = 0;
    size_t w_r1  = w_a1 + B * 4096;
    size_t w_us1 = w_r1 + B * 3969;

    dim3 blk(256);
    k_L01<<<dim3(16, B), blk, 0, stream>>>(
        u, f, a, c0w, c0b, c1w, c1b, r1w, r3w,
        out + off_us0, out + off_d0, out + off_f, out + off_a,
        out + off_d1, ws + w_a1, ws + w_r1, ws + w_us1);

    k_coarse<<<dim3(1024), blk, 0, stream>>>(
        ws + w_a1, ws + w_r1, ws + w_us1, out + off_us0,
        r1w, r3w, c1w, c1b, c0w, c0b, tw,
        out + off_d2, out + off_d3, out + off_d4);
}

// Round 6
// 506.322 us; speedup vs baseline: 1.0439x; 1.0439x over previous
//
#include <hip/hip_runtime.h>
#include <cmath>

#define BATCH 1024

// ---------------- Fused Level 0 + Level 1, 8-row stripes, high occupancy ----------------
// LDS 20.3 KB -> 7 blocks/CU; declare 7 waves/EU so regalloc gets 73 VGPR (prefetch fits).
__global__ __launch_bounds__(256, 7) void k_L01(
    const float* __restrict__ u, const float* __restrict__ f, const float* __restrict__ a,
    const float* __restrict__ c0w, const float* __restrict__ c0b,
    const float* __restrict__ c1w, const float* __restrict__ c1b,
    const float* __restrict__ r1w, const float* __restrict__ r3w,
    float* __restrict__ out_us0, float* __restrict__ out_diva0,
    float* __restrict__ out_f, float* __restrict__ out_a,
    float* __restrict__ out_diva1,
    float* __restrict__ ws_a1, float* __restrict__ ws_r1, float* __restrict__ ws_us1)
{
    const int b = blockIdx.y;
    const int bx = blockIdx.x;      // 0..15
    const int Y0 = bx * 8;          // level-0 row base
    const int y0 = bx * 4;          // level-1 row base
    const int tid = threadIdx.x;
    const int tx = tid & 127, ty = tid >> 7;

    __shared__ float asrc[14][128];  // a rows Y0-2 .. Y0+11 (clamped)
    __shared__ float td0[10][128];   // tanh(diva0) rows Y0-1 .. Y0+8 (valid only)
    __shared__ float r0s[9][128];    // r0 rows Y0 .. Y0+8 (valid only)
    __shared__ float a1s[7][68];     // a1 rows y0-1..y0+5 (clamped), cols -1..64 (clamped)
    __shared__ float td1[6][64];     // tanh(diva1) rows y0-1..y0+4 (valid), cols 0..62

    // ---- A: stage a rows (float4, fully coalesced) ----
    {
        const float4* ab4 = reinterpret_cast<const float4*>(a + (size_t)b * 16384);
        float4* s4 = reinterpret_cast<float4*>(&asrc[0][0]);
        const int c4 = tid & 31, r4 = tid >> 5;
        #pragma unroll
        for (int r = r4; r < 14; r += 8) {
            int g = Y0 - 2 + r; g = g < 0 ? 0 : (g > 127 ? 127 : g);
            s4[r * 32 + c4] = ab4[g * 32 + c4];
        }
    }

    // ---- prefetch u/f for phase C (issued alongside staging loads; HBM latency
    //      hides under phases B/P/D) ----
    const size_t rowbase = (size_t)b * 16129;
    float ur[5], fr[5];
    #pragma unroll
    for (int k = 0; k < 5; k++) {
        int rr = ty + 2 * k;
        int g = Y0 + rr;
        if (rr < 9 && g <= 126 && tx < 127) {
            size_t idx = rowbase + (size_t)g * 127 + tx;
            ur[k] = u[idx];
            fr[k] = f[idx];
        }
    }
    __syncthreads();

    const float w00 = c1w[0], w01 = c1w[1], w10 = c1w[2], w11 = c1w[3], b1 = c1b[0];

    // ---- B: td0 rows Y0-1..Y0+8 ----
    #pragma unroll
    for (int r = ty; r < 10; r += 2) {
        int g = Y0 - 1 + r;
        if (g >= 0 && g <= 126 && tx < 127) {
            float d = asrc[r + 1][tx] * w00 + asrc[r + 1][tx + 1] * w01
                    + asrc[r + 2][tx] * w10 + asrc[r + 2][tx + 1] * w11 + b1;
            td0[r][tx] = tanhf(d);
        }
    }
    // ---- P: a passthrough rows Y0..Y0+7 (float4) ----
    {
        float4* oa4 = reinterpret_cast<float4*>(out_a + (size_t)b * 16384);
        const float4* s4 = reinterpret_cast<const float4*>(&asrc[0][0]);
        const int c4 = tid & 31, r4 = tid >> 5;
        oa4[(Y0 + r4) * 32 + c4] = s4[(r4 + 2) * 32 + c4];
    }
    // ---- D: a1 restriction (reads asrc only) ----
    const float q00 = r1w[0], q01 = r1w[1], q10 = r1w[2], q11 = r1w[3];
    {
        const int tx2 = tid & 63, ty2 = tid >> 6;
        #pragma unroll
        for (int r = ty2; r < 7; r += 4)
            for (int c = tx2; c < 66; c += 64) {
                int ay = y0 - 1 + r; ay = ay < 0 ? 0 : (ay > 63 ? 63 : ay);
                int ax = c - 1; ax = ax < 0 ? 0 : (ax > 63 ? 63 : ax);
                int la = 2 * ay - (Y0 - 2);
                a1s[r][c] = asrc[la][2 * ax] * q00 + asrc[la][2 * ax + 1] * q01
                          + asrc[la + 1][2 * ax] * q10 + asrc[la + 1][2 * ax + 1] * q11;
            }
    }
    __syncthreads();

    // ---- C: r0s + level-0 outputs (consumes prefetched u/f) ----
    const float c0b0 = c0b[0];
    #pragma unroll
    for (int k = 0; k < 5; k++) {
        int rr = ty + 2 * k;
        if (rr >= 9) break;
        int g = Y0 + rr;
        if (g > 126 || tx >= 127) continue;
        float diva = asrc[rr + 2][tx] * w00 + asrc[rr + 2][tx + 1] * w01
                   + asrc[rr + 3][tx] * w10 + asrc[rr + 3][tx + 1] * w11 + b1;
        size_t idx = rowbase + (size_t)g * 127 + tx;
        float uv = ur[k], fv = fr[k];
        float rv = fv - diva * uv;
        r0s[rr][tx] = rv;
        if (rr < 8) {
            float s = c0b0;
            #pragma unroll
            for (int ky = 0; ky < 3; ky++) {
                int sy = g - 1 + ky; sy = sy < 0 ? 0 : (sy > 126 ? 126 : sy);
                int lr = sy - (Y0 - 1);
                #pragma unroll
                for (int kx = 0; kx < 3; kx++) {
                    int sx = tx - 1 + kx; sx = sx < 0 ? 0 : (sx > 126 ? 126 : sx);
                    s += c0w[ky * 3 + kx] * td0[lr][sx];
                }
            }
            out_diva0[idx] = diva;
            out_us0[idx] = uv + s * rv;
            out_f[idx] = fv;
        }
    }

    // ---- E: a1 out + td1 ----
    const float v00 = c1w[4], v01 = c1w[5], v10 = c1w[6], v11 = c1w[7], b2 = c1b[1];
    {
        const int tx2 = tid & 63, ty2 = tid >> 6;
        ws_a1[(size_t)b * 4096 + (size_t)(y0 + ty2) * 64 + tx2] = a1s[ty2 + 1][tx2 + 1];
        #pragma unroll
        for (int r = ty2; r < 6; r += 4) {
            int dy = y0 - 1 + r;
            if (dy >= 0 && dy <= 62 && tx2 < 63) {
                float d = a1s[r][tx2 + 1] * v00 + a1s[r][tx2 + 2] * v01
                        + a1s[r + 1][tx2 + 1] * v10 + a1s[r + 1][tx2 + 2] * v11 + b2;
                td1[r][tx2] = tanhf(d);
            }
        }
    }
    __syncthreads();

    // ---- F: level-1 outputs rows y0..y0+3 ----
    {
        const int tx2 = tid & 63, ty2 = tid >> 6;
        const int y = y0 + ty2;
        if (y <= 62 && tx2 < 63) {
            float diva = a1s[ty2 + 1][tx2 + 1] * v00 + a1s[ty2 + 1][tx2 + 2] * v01
                       + a1s[ty2 + 2][tx2 + 1] * v10 + a1s[ty2 + 2][tx2 + 2] * v11 + b2;
            float rv = 0.f;
            #pragma unroll
            for (int p = 0; p < 3; p++)
                #pragma unroll
                for (int q = 0; q < 3; q++)
                    rv += r3w[p * 3 + q] * r0s[2 * ty2 + p][2 * tx2 + q];
            float s = c0b[1];
            #pragma unroll
            for (int ky = 0; ky < 3; ky++) {
                int sy = y - 1 + ky; sy = sy < 0 ? 0 : (sy > 62 ? 62 : sy);
                int lr = sy - (y0 - 1);
                #pragma unroll
                for (int kx = 0; kx < 3; kx++) {
                    int sx = tx2 - 1 + kx; sx = sx < 0 ? 0 : (sx > 62 ? 62 : sx);
                    s += c0w[9 + ky * 3 + kx] * td1[lr][sx];
                }
            }
            size_t idx = (size_t)b * 3969 + (size_t)y * 63 + tx2;
            out_diva1[idx] = diva;
            ws_r1[idx] = rv;
            ws_us1[idx] = s * rv;
        }
    }
}

// ---------------- levels 2..4 helper ----------------
template<int N, int NA, int PA, int PD>
__device__ __forceinline__ void level_step(
    const float* ap, const float* rp, float* ac, float* rc, float* us, float* td,
    const float* __restrict__ r1w, const float* __restrict__ r3w,
    const float* __restrict__ c1w, float c1b_,
    const float* __restrict__ c0w, float c0b_,
    float* __restrict__ diva_out, int tid)
{
    const float q00 = r1w[0], q01 = r1w[1], q10 = r1w[2], q11 = r1w[3];
    for (int idx = tid; idx < NA * NA; idx += 256) {
        int y = idx / NA, x = idx % NA;
        const float* p = ap + 2 * y * PA + 2 * x;
        ac[idx] = p[0] * q00 + p[1] * q01 + p[PA] * q10 + p[PA + 1] * q11;
    }
    __syncthreads();
    const float w00 = c1w[0], w01 = c1w[1], w10 = c1w[2], w11 = c1w[3];
    for (int idx = tid; idx < N * N; idx += 256) {
        int y = idx / N, x = idx % N;
        float d = ac[y * NA + x] * w00 + ac[y * NA + x + 1] * w01
                + ac[(y + 1) * NA + x] * w10 + ac[(y + 1) * NA + x + 1] * w11 + c1b_;
        td[idx] = tanhf(d);
        diva_out[idx] = d;
    }
    __syncthreads();
    for (int idx = tid; idx < N * N; idx += 256) {
        int y = idx / N, x = idx % N;
        float rv = 0.f;
        #pragma unroll
        for (int p = 0; p < 3; p++)
            #pragma unroll
            for (int q = 0; q < 3; q++)
                rv += r3w[p * 3 + q] * rp[(2 * y + p) * PD + 2 * x + q];
        float s = c0b_;
        #pragma unroll
        for (int ky = 0; ky < 3; ky++) {
            int sy = y - 1 + ky; sy = sy < 0 ? 0 : (sy > N - 1 ? N - 1 : sy);
            #pragma unroll
            for (int kx = 0; kx < 3; kx++) {
                int sx = x - 1 + kx; sx = sx < 0 ? 0 : (sx > N - 1 ? N - 1 : sx);
                s += c0w[ky * 3 + kx] * td[sy * N + sx];
            }
        }
        rc[idx] = rv;
        us[idx] = s * rv;
    }
    __syncthreads();
}

template<int NO, int NI>
__device__ __forceinline__ void prolong_step(
    float* uo, const float* ui, const float* __restrict__ tw9, int tid)
{
    for (int idx = tid; idx < NO * NO; idx += 256) {
        int y = idx / NO, x = idx % NO;
        float acc = 0.f;
        #pragma unroll
        for (int ky = 0; ky < 3; ky++) {
            int sy = y - ky;
            if (sy & 1) continue;
            int iy = sy >> 1;
            if (iy < 0 || iy >= NI) continue;
            #pragma unroll
            for (int kx = 0; kx < 3; kx++) {
                int sx = x - kx;
                if (sx & 1) continue;
                int ix = sx >> 1;
                if (ix < 0 || ix >= NI) continue;
                acc += tw9[ky * 3 + kx] * ui[iy * NI + ix];
            }
        }
        uo[idx] += acc;
    }
    __syncthreads();
}

// ---------------- Levels 2..4 + prolong 4->3->2 (one block per image, 19 KB LDS) ----------------
__global__ __launch_bounds__(256, 4) void k_coarse(
    const float* __restrict__ a1, const float* __restrict__ r1,
    const float* __restrict__ r1w, const float* __restrict__ r3w,
    const float* __restrict__ c1w, const float* __restrict__ c1b,
    const float* __restrict__ c0w, const float* __restrict__ c0b,
    const float* __restrict__ tw,
    float* __restrict__ diva2, float* __restrict__ diva3, float* __restrict__ diva4,
    float* __restrict__ us2_out)
{
    const int b = blockIdx.x;
    const int tid = threadIdx.x;
    __shared__ float aB[32 * 32];
    __shared__ float rB[31 * 31];
    __shared__ float aC[16 * 16];
    __shared__ float rC[15 * 15];
    __shared__ float aD[8 * 8];
    __shared__ float rD[7 * 7];
    __shared__ float us2s[31 * 31];
    __shared__ float us3s[15 * 15];
    __shared__ float us4s[7 * 7];
    __shared__ float td[31 * 31];

    // level 2 reads a1/r1 straight from global (restriction has no reuse)
    level_step<31, 32, 64, 63>(a1 + (size_t)b * 4096, r1 + (size_t)b * 3969,
        aB, rB, us2s, td,
        r1w + 4, r3w + 9, c1w + 8, c1b[2], c0w + 18, c0b[2],
        diva2 + (size_t)b * 961, tid);
    level_step<15, 16, 32, 31>(aB, rB, aC, rC, us3s, td,
        r1w + 8, r3w + 18, c1w + 12, c1b[3], c0w + 27, c0b[3],
        diva3 + (size_t)b * 225, tid);
    level_step<7, 8, 16, 15>(aC, rC, aD, rD, us4s, td,
        r1w + 12, r3w + 27, c1w + 16, c1b[4], c0w + 36, c0b[4],
        diva4 + (size_t)b * 49, tid);

    prolong_step<15, 7>(us3s, us4s, tw + 27, tid);
    prolong_step<31, 15>(us2s, us3s, tw + 18, tid);

    for (int i = tid; i < 961; i += 256)
        us2_out[(size_t)b * 961 + i] = us2s[i];
}

// ---------------- Fused prolong: us1'=us1+convT(us2') in LDS, then us0 += convT(us1') ----------------
__global__ __launch_bounds__(256, 8) void k_prolong2(
    float* __restrict__ us0, const float* __restrict__ us1, const float* __restrict__ us2,
    const float* __restrict__ tw)   // tw+0: level0<-1 weights, tw+9: level1<-2 weights
{
    const int b = blockIdx.y;
    const int bx = blockIdx.x;       // 0..7
    const int Y0 = bx * 16;          // us0 row base
    const int y0 = bx * 8;           // us1 row base
    const int tid = threadIdx.x;
    __shared__ float us2s[6][32];    // us2' rows 4bx-2 .. 4bx+3 (valid only)
    __shared__ float us1p[9][64];    // us1' rows y0-1 .. y0+7 (valid only)

    const int tx2 = tid & 63, ty2 = tid >> 6;

    // prefetch us1 rows this thread will own (issued before first barrier)
    float u1r[3];
    {
        const float* i1 = us1 + (size_t)b * 3969;
        #pragma unroll
        for (int j = 0; j < 3; j++) {
            int r = ty2 + 4 * j;
            int iy = y0 - 1 + r;
            if (r < 9 && iy >= 0 && iy <= 62 && tx2 < 63)
                u1r[j] = i1[iy * 63 + tx2];
        }
    }
    {
        const float* i2 = us2 + (size_t)b * 961;
        const int tx3 = tid & 31, ty3 = tid >> 5;
        if (ty3 < 6 && tx3 < 31) {
            int jy = 4 * bx - 2 + ty3;
            if (jy >= 0 && jy <= 30) us2s[ty3][tx3] = i2[jy * 31 + tx3];
        }
    }
    __syncthreads();

    const float* t1 = tw + 9;
    {
        #pragma unroll
        for (int j = 0; j < 3; j++) {
            int r = ty2 + 4 * j;
            int iy = y0 - 1 + r;
            if (r >= 9 || iy < 0 || iy > 62 || tx2 >= 63) continue;
            float acc = u1r[j];
            #pragma unroll
            for (int ky = 0; ky < 3; ky++) {
                int sy = iy - ky;
                if ((sy & 1) || sy < 0) continue;
                int jy = sy >> 1;
                if (jy > 30) continue;
                int lr = jy - (4 * bx - 2);
                #pragma unroll
                for (int kx = 0; kx < 3; kx++) {
                    int sx = tx2 - kx;
                    if ((sx & 1) || sx < 0) continue;
                    int jx = sx >> 1;
                    if (jx > 30) continue;
                    acc += t1[ky * 3 + kx] * us2s[lr][jx];
                }
            }
            us1p[r][tx2] = acc;
        }
    }
    __syncthreads();

    const float* t0 = tw;
    {
        float* o0 = us0 + (size_t)b * 16129;
        const int tx = tid & 127, ty = tid >> 7;
        #pragma unroll
        for (int row = ty; row < 16; row += 2) {
            int y = Y0 + row;
            if (y > 126 || tx >= 127) continue;
            float acc = 0.f;
            #pragma unroll
            for (int ky = 0; ky < 3; ky++) {
                int sy = y - ky;
                if ((sy & 1) || sy < 0) continue;
                int iy = sy >> 1;
                if (iy > 62) continue;
                int lr = iy - (y0 - 1);
                #pragma unroll
                for (int kx = 0; kx < 3; kx++) {
                    int sx = tx - kx;
                    if ((sx & 1) || sx < 0) continue;
                    int ix = sx >> 1;
                    if (ix > 62) continue;
                    acc += t0[ky * 3 + kx] * us1p[lr][ix];
                }
            }
            o0[(size_t)y * 127 + tx] += acc;
        }
    }
}

extern "C" void kernel_launch(void* const* d_in, const int* in_sizes, int n_in,
                              void* d_out, int out_size, void* d_ws, size_t ws_size,
                              hipStream_t stream) {
    const float* u   = (const float*)d_in[0];
    const float* f   = (const float*)d_in[1];
    const float* a   = (const float*)d_in[2];
    const float* c0w = (const float*)d_in[3];
    const float* c0b = (const float*)d_in[4];
    const float* c1w = (const float*)d_in[5];
    const float* c1b = (const float*)d_in[6];
    const float* r1w = (const float*)d_in[7];
    const float* r3w = (const float*)d_in[8];
    const float* tw  = (const float*)d_in[9];
    float* out = (float*)d_out;
    float* ws  = (float*)d_ws;
    const size_t B = BATCH;

    // d_out layout: us0, f, a, diva0..diva4
    size_t off_us0 = 0;
    size_t off_f   = B * 16129;
    size_t off_a   = off_f + B * 16129;
    size_t off_d0  = off_a + B * 16384;
    size_t off_d1  = off_d0 + B * 16129;
    size_t off_d2  = off_d1 + B * 3969;
    size_t off_d3  = off_d2 + B * 961;
    size_t off_d4  = off_d3 + B * 225;

    // ws layout: a1, r1, us1, us2
    size_t w_a1  = 0;
    size_t w_r1  = w_a1 + B * 4096;
    size_t w_us1 = w_r1 + B * 3969;
    size_t w_us2 = w_us1 + B * 3969;

    dim3 blk(256);
    k_L01<<<dim3(16, B), blk, 0, stream>>>(
        u, f, a, c0w, c0b, c1w, c1b, r1w, r3w,
        out + off_us0, out + off_d0, out + off_f, out + off_a,
        out + off_d1, ws + w_a1, ws + w_r1, ws + w_us1);

    k_coarse<<<dim3(1024), blk, 0, stream>>>(
        ws + w_a1, ws + w_r1, r1w, r3w, c1w, c1b, c0w, c0b, tw,
        out + off_d2, out + off_d3, out + off_d4, ws + w_us2);

    k_prolong2<<<dim3(8, B), blk, 0, stream>>>(
        out + off_us0, ws + w_us1, ws + w_us2, tw);
}

// Round 7
// 504.037 us; speedup vs baseline: 1.0486x; 1.0045x over previous
//
#include <hip/hip_runtime.h>
#include <cmath>

#define BATCH 1024

// Fast tanh: tanh(x) = sign(x) * (1 - e)/(1 + e), e = exp(-2|x|).
// ~8 VALU ops vs ~25+call for __ocml_tanh_f32; max err ~3 ulp.
__device__ __forceinline__ float fast_tanh(float x) {
    float ax = fabsf(x);
    float e = __expf(-2.0f * ax);
    float t = __fdividef(1.0f - e, 1.0f + e);
    return copysignf(t, x);
}

// ---------------- Fused Level 0 + Level 1, 8-row stripes, high occupancy ----------------
// LDS 20.3 KB -> 7 blocks/CU; declare 7 waves/EU so regalloc gets 73 VGPR (prefetch fits).
__global__ __launch_bounds__(256, 7) void k_L01(
    const float* __restrict__ u, const float* __restrict__ f, const float* __restrict__ a,
    const float* __restrict__ c0w, const float* __restrict__ c0b,
    const float* __restrict__ c1w, const float* __restrict__ c1b,
    const float* __restrict__ r1w, const float* __restrict__ r3w,
    float* __restrict__ out_us0, float* __restrict__ out_diva0,
    float* __restrict__ out_f, float* __restrict__ out_a,
    float* __restrict__ out_diva1,
    float* __restrict__ ws_a1, float* __restrict__ ws_r1, float* __restrict__ ws_us1)
{
    const int b = blockIdx.y;
    const int bx = blockIdx.x;      // 0..15
    const int Y0 = bx * 8;          // level-0 row base
    const int y0 = bx * 4;          // level-1 row base
    const int tid = threadIdx.x;
    const int tx = tid & 127, ty = tid >> 7;

    __shared__ float asrc[14][128];  // a rows Y0-2 .. Y0+11 (clamped)
    __shared__ float td0[10][128];   // tanh(diva0) rows Y0-1 .. Y0+8 (valid only)
    __shared__ float r0s[9][128];    // r0 rows Y0 .. Y0+8 (valid only)
    __shared__ float a1s[7][68];     // a1 rows y0-1..y0+5 (clamped), cols -1..64 (clamped)
    __shared__ float td1[6][64];     // tanh(diva1) rows y0-1..y0+4 (valid), cols 0..62

    // ---- A: stage a rows (float4, fully coalesced) ----
    {
        const float4* ab4 = reinterpret_cast<const float4*>(a + (size_t)b * 16384);
        float4* s4 = reinterpret_cast<float4*>(&asrc[0][0]);
        const int c4 = tid & 31, r4 = tid >> 5;
        #pragma unroll
        for (int r = r4; r < 14; r += 8) {
            int g = Y0 - 2 + r; g = g < 0 ? 0 : (g > 127 ? 127 : g);
            s4[r * 32 + c4] = ab4[g * 32 + c4];
        }
    }

    // ---- prefetch u/f for phase C (issued alongside staging loads; HBM latency
    //      hides under phases B/P/D) ----
    const size_t rowbase = (size_t)b * 16129;
    float ur[5], fr[5];
    #pragma unroll
    for (int k = 0; k < 5; k++) {
        int rr = ty + 2 * k;
        int g = Y0 + rr;
        if (rr < 9 && g <= 126 && tx < 127) {
            size_t idx = rowbase + (size_t)g * 127 + tx;
            ur[k] = u[idx];
            fr[k] = f[idx];
        }
    }
    __syncthreads();

    const float w00 = c1w[0], w01 = c1w[1], w10 = c1w[2], w11 = c1w[3], b1 = c1b[0];

    // ---- B: td0 rows Y0-1..Y0+8 ----
    #pragma unroll
    for (int r = ty; r < 10; r += 2) {
        int g = Y0 - 1 + r;
        if (g >= 0 && g <= 126 && tx < 127) {
            float d = asrc[r + 1][tx] * w00 + asrc[r + 1][tx + 1] * w01
                    + asrc[r + 2][tx] * w10 + asrc[r + 2][tx + 1] * w11 + b1;
            td0[r][tx] = fast_tanh(d);
        }
    }
    // ---- P: a passthrough rows Y0..Y0+7 (float4) ----
    {
        float4* oa4 = reinterpret_cast<float4*>(out_a + (size_t)b * 16384);
        const float4* s4 = reinterpret_cast<const float4*>(&asrc[0][0]);
        const int c4 = tid & 31, r4 = tid >> 5;
        oa4[(Y0 + r4) * 32 + c4] = s4[(r4 + 2) * 32 + c4];
    }
    // ---- D: a1 restriction (reads asrc only) ----
    const float q00 = r1w[0], q01 = r1w[1], q10 = r1w[2], q11 = r1w[3];
    {
        const int tx2 = tid & 63, ty2 = tid >> 6;
        #pragma unroll
        for (int r = ty2; r < 7; r += 4)
            for (int c = tx2; c < 66; c += 64) {
                int ay = y0 - 1 + r; ay = ay < 0 ? 0 : (ay > 63 ? 63 : ay);
                int ax = c - 1; ax = ax < 0 ? 0 : (ax > 63 ? 63 : ax);
                int la = 2 * ay - (Y0 - 2);
                a1s[r][c] = asrc[la][2 * ax] * q00 + asrc[la][2 * ax + 1] * q01
                          + asrc[la + 1][2 * ax] * q10 + asrc[la + 1][2 * ax + 1] * q11;
            }
    }
    __syncthreads();

    // ---- C: r0s + level-0 outputs (consumes prefetched u/f) ----
    const float c0b0 = c0b[0];
    #pragma unroll
    for (int k = 0; k < 5; k++) {
        int rr = ty + 2 * k;
        if (rr >= 9) break;
        int g = Y0 + rr;
        if (g > 126 || tx >= 127) continue;
        float diva = asrc[rr + 2][tx] * w00 + asrc[rr + 2][tx + 1] * w01
                   + asrc[rr + 3][tx] * w10 + asrc[rr + 3][tx + 1] * w11 + b1;
        size_t idx = rowbase + (size_t)g * 127 + tx;
        float uv = ur[k], fv = fr[k];
        float rv = fv - diva * uv;
        r0s[rr][tx] = rv;
        if (rr < 8) {
            float s = c0b0;
            #pragma unroll
            for (int ky = 0; ky < 3; ky++) {
                int sy = g - 1 + ky; sy = sy < 0 ? 0 : (sy > 126 ? 126 : sy);
                int lr = sy - (Y0 - 1);
                #pragma unroll
                for (int kx = 0; kx < 3; kx++) {
                    int sx = tx - 1 + kx; sx = sx < 0 ? 0 : (sx > 126 ? 126 : sx);
                    s += c0w[ky * 3 + kx] * td0[lr][sx];
                }
            }
            out_diva0[idx] = diva;
            out_us0[idx] = uv + s * rv;
            out_f[idx] = fv;
        }
    }

    // ---- E: a1 out + td1 ----
    const float v00 = c1w[4], v01 = c1w[5], v10 = c1w[6], v11 = c1w[7], b2 = c1b[1];
    {
        const int tx2 = tid & 63, ty2 = tid >> 6;
        ws_a1[(size_t)b * 4096 + (size_t)(y0 + ty2) * 64 + tx2] = a1s[ty2 + 1][tx2 + 1];
        #pragma unroll
        for (int r = ty2; r < 6; r += 4) {
            int dy = y0 - 1 + r;
            if (dy >= 0 && dy <= 62 && tx2 < 63) {
                float d = a1s[r][tx2 + 1] * v00 + a1s[r][tx2 + 2] * v01
                        + a1s[r + 1][tx2 + 1] * v10 + a1s[r + 1][tx2 + 2] * v11 + b2;
                td1[r][tx2] = fast_tanh(d);
            }
        }
    }
    __syncthreads();

    // ---- F: level-1 outputs rows y0..y0+3 ----
    {
        const int tx2 = tid & 63, ty2 = tid >> 6;
        const int y = y0 + ty2;
        if (y <= 62 && tx2 < 63) {
            float diva = a1s[ty2 + 1][tx2 + 1] * v00 + a1s[ty2 + 1][tx2 + 2] * v01
                       + a1s[ty2 + 2][tx2 + 1] * v10 + a1s[ty2 + 2][tx2 + 2] * v11 + b2;
            float rv = 0.f;
            #pragma unroll
            for (int p = 0; p < 3; p++)
                #pragma unroll
                for (int q = 0; q < 3; q++)
                    rv += r3w[p * 3 + q] * r0s[2 * ty2 + p][2 * tx2 + q];
            float s = c0b[1];
            #pragma unroll
            for (int ky = 0; ky < 3; ky++) {
                int sy = y - 1 + ky; sy = sy < 0 ? 0 : (sy > 62 ? 62 : sy);
                int lr = sy - (y0 - 1);
                #pragma unroll
                for (int kx = 0; kx < 3; kx++) {
                    int sx = tx2 - 1 + kx; sx = sx < 0 ? 0 : (sx > 62 ? 62 : sx);
                    s += c0w[9 + ky * 3 + kx] * td1[lr][sx];
                }
            }
            size_t idx = (size_t)b * 3969 + (size_t)y * 63 + tx2;
            out_diva1[idx] = diva;
            ws_r1[idx] = rv;
            ws_us1[idx] = s * rv;
        }
    }
}

// ---------------- levels 2..4 helper ----------------
template<int N, int NA, int PA, int PD>
__device__ __forceinline__ void level_step(
    const float* ap, const float* rp, float* ac, float* rc, float* us, float* td,
    const float* __restrict__ r1w, const float* __restrict__ r3w,
    const float* __restrict__ c1w, float c1b_,
    const float* __restrict__ c0w, float c0b_,
    float* __restrict__ diva_out, int tid)
{
    const float q00 = r1w[0], q01 = r1w[1], q10 = r1w[2], q11 = r1w[3];
    for (int idx = tid; idx < NA * NA; idx += 256) {
        int y = idx / NA, x = idx % NA;
        const float* p = ap + 2 * y * PA + 2 * x;
        ac[idx] = p[0] * q00 + p[1] * q01 + p[PA] * q10 + p[PA + 1] * q11;
    }
    __syncthreads();
    const float w00 = c1w[0], w01 = c1w[1], w10 = c1w[2], w11 = c1w[3];
    for (int idx = tid; idx < N * N; idx += 256) {
        int y = idx / N, x = idx % N;
        float d = ac[y * NA + x] * w00 + ac[y * NA + x + 1] * w01
                + ac[(y + 1) * NA + x] * w10 + ac[(y + 1) * NA + x + 1] * w11 + c1b_;
        td[idx] = fast_tanh(d);
        diva_out[idx] = d;
    }
    __syncthreads();
    for (int idx = tid; idx < N * N; idx += 256) {
        int y = idx / N, x = idx % N;
        float rv = 0.f;
        #pragma unroll
        for (int p = 0; p < 3; p++)
            #pragma unroll
            for (int q = 0; q < 3; q++)
                rv += r3w[p * 3 + q] * rp[(2 * y + p) * PD + 2 * x + q];
        float s = c0b_;
        #pragma unroll
        for (int ky = 0; ky < 3; ky++) {
            int sy = y - 1 + ky; sy = sy < 0 ? 0 : (sy > N - 1 ? N - 1 : sy);
            #pragma unroll
            for (int kx = 0; kx < 3; kx++) {
                int sx = x - 1 + kx; sx = sx < 0 ? 0 : (sx > N - 1 ? N - 1 : sx);
                s += c0w[ky * 3 + kx] * td[sy * N + sx];
            }
        }
        rc[idx] = rv;
        us[idx] = s * rv;
    }
    __syncthreads();
}

template<int NO, int NI>
__device__ __forceinline__ void prolong_step(
    float* uo, const float* ui, const float* __restrict__ tw9, int tid)
{
    for (int idx = tid; idx < NO * NO; idx += 256) {
        int y = idx / NO, x = idx % NO;
        float acc = 0.f;
        #pragma unroll
        for (int ky = 0; ky < 3; ky++) {
            int sy = y - ky;
            if (sy & 1) continue;
            int iy = sy >> 1;
            if (iy < 0 || iy >= NI) continue;
            #pragma unroll
            for (int kx = 0; kx < 3; kx++) {
                int sx = x - kx;
                if (sx & 1) continue;
                int ix = sx >> 1;
                if (ix < 0 || ix >= NI) continue;
                acc += tw9[ky * 3 + kx] * ui[iy * NI + ix];
            }
        }
        uo[idx] += acc;
    }
    __syncthreads();
}

// ---------------- Levels 2..4 + prolong 4->3->2 (one block per image, 19 KB LDS) ----------------
__global__ __launch_bounds__(256, 4) void k_coarse(
    const float* __restrict__ a1, const float* __restrict__ r1,
    const float* __restrict__ r1w, const float* __restrict__ r3w,
    const float* __restrict__ c1w, const float* __restrict__ c1b,
    const float* __restrict__ c0w, const float* __restrict__ c0b,
    const float* __restrict__ tw,
    float* __restrict__ diva2, float* __restrict__ diva3, float* __restrict__ diva4,
    float* __restrict__ us2_out)
{
    const int b = blockIdx.x;
    const int tid = threadIdx.x;
    __shared__ float aB[32 * 32];
    __shared__ float rB[31 * 31];
    __shared__ float aC[16 * 16];
    __shared__ float rC[15 * 15];
    __shared__ float aD[8 * 8];
    __shared__ float rD[7 * 7];
    __shared__ float us2s[31 * 31];
    __shared__ float us3s[15 * 15];
    __shared__ float us4s[7 * 7];
    __shared__ float td[31 * 31];

    // level 2 reads a1/r1 straight from global (restriction has no reuse)
    level_step<31, 32, 64, 63>(a1 + (size_t)b * 4096, r1 + (size_t)b * 3969,
        aB, rB, us2s, td,
        r1w + 4, r3w + 9, c1w + 8, c1b[2], c0w + 18, c0b[2],
        diva2 + (size_t)b * 961, tid);
    level_step<15, 16, 32, 31>(aB, rB, aC, rC, us3s, td,
        r1w + 8, r3w + 18, c1w + 12, c1b[3], c0w + 27, c0b[3],
        diva3 + (size_t)b * 225, tid);
    level_step<7, 8, 16, 15>(aC, rC, aD, rD, us4s, td,
        r1w + 12, r3w + 27, c1w + 16, c1b[4], c0w + 36, c0b[4],
        diva4 + (size_t)b * 49, tid);

    prolong_step<15, 7>(us3s, us4s, tw + 27, tid);
    prolong_step<31, 15>(us2s, us3s, tw + 18, tid);

    for (int i = tid; i < 961; i += 256)
        us2_out[(size_t)b * 961 + i] = us2s[i];
}

// ---------------- Fused prolong: us1'=us1+convT(us2') in LDS, then us0 += convT(us1') ----------------
__global__ __launch_bounds__(256, 7) void k_prolong2(
    float* __restrict__ us0, const float* __restrict__ us1, const float* __restrict__ us2,
    const float* __restrict__ tw)   // tw+0: level0<-1 weights, tw+9: level1<-2 weights
{
    const int b = blockIdx.y;
    const int bx = blockIdx.x;       // 0..7
    const int Y0 = bx * 16;          // us0 row base
    const int y0 = bx * 8;           // us1 row base
    const int tid = threadIdx.x;
    __shared__ float us2s[6][32];    // us2' rows 4bx-2 .. 4bx+3 (valid only)
    __shared__ float us1p[9][64];    // us1' rows y0-1 .. y0+7 (valid only)

    const int tx2 = tid & 63, ty2 = tid >> 6;
    const int tx = tid & 127, ty = tid >> 7;

    // prefetch us1 rows this thread will own (issued before first barrier)
    float u1r[3];
    {
        const float* i1 = us1 + (size_t)b * 3969;
        #pragma unroll
        for (int j = 0; j < 3; j++) {
            int r = ty2 + 4 * j;
            int iy = y0 - 1 + r;
            if (r < 9 && iy >= 0 && iy <= 62 && tx2 < 63)
                u1r[j] = i1[iy * 63 + tx2];
        }
    }
    // prefetch us0 values this thread will RMW (read hides under us2s/us1p phases)
    float o0r[8];
    float* o0 = us0 + (size_t)b * 16129;
    #pragma unroll
    for (int j = 0; j < 8; j++) {
        int y = Y0 + ty + 2 * j;
        if (y <= 126 && tx < 127) o0r[j] = o0[(size_t)y * 127 + tx];
    }
    {
        const float* i2 = us2 + (size_t)b * 961;
        const int tx3 = tid & 31, ty3 = tid >> 5;
        if (ty3 < 6 && tx3 < 31) {
            int jy = 4 * bx - 2 + ty3;
            if (jy >= 0 && jy <= 30) us2s[ty3][tx3] = i2[jy * 31 + tx3];
        }
    }
    __syncthreads();

    const float* t1 = tw + 9;
    {
        #pragma unroll
        for (int j = 0; j < 3; j++) {
            int r = ty2 + 4 * j;
            int iy = y0 - 1 + r;
            if (r >= 9 || iy < 0 || iy > 62 || tx2 >= 63) continue;
            float acc = u1r[j];
            #pragma unroll
            for (int ky = 0; ky < 3; ky++) {
                int sy = iy - ky;
                if ((sy & 1) || sy < 0) continue;
                int jy = sy >> 1;
                if (jy > 30) continue;
                int lr = jy - (4 * bx - 2);
                #pragma unroll
                for (int kx = 0; kx < 3; kx++) {
                    int sx = tx2 - kx;
                    if ((sx & 1) || sx < 0) continue;
                    int jx = sx >> 1;
                    if (jx > 30) continue;
                    acc += t1[ky * 3 + kx] * us2s[lr][jx];
                }
            }
            us1p[r][tx2] = acc;
        }
    }
    __syncthreads();

    const float* t0 = tw;
    {
        #pragma unroll
        for (int j = 0; j < 8; j++) {
            int row = ty + 2 * j;
            int y = Y0 + row;
            if (y > 126 || tx >= 127) continue;
            float acc = o0r[j];
            #pragma unroll
            for (int ky = 0; ky < 3; ky++) {
                int sy = y - ky;
                if ((sy & 1) || sy < 0) continue;
                int iy = sy >> 1;
                if (iy > 62) continue;
                int lr = iy - (y0 - 1);
                #pragma unroll
                for (int kx = 0; kx < 3; kx++) {
                    int sx = tx - kx;
                    if ((sx & 1) || sx < 0) continue;
                    int ix = sx >> 1;
                    if (ix > 62) continue;
                    acc += t0[ky * 3 + kx] * us1p[lr][ix];
                }
            }
            o0[(size_t)y * 127 + tx] = acc;
        }
    }
}

extern "C" void kernel_launch(void* const* d_in, const int* in_sizes, int n_in,
                              void* d_out, int out_size, void* d_ws, size_t ws_size,
                              hipStream_t stream) {
    const float* u   = (const float*)d_in[0];
    const float* f   = (const float*)d_in[1];
    const float* a   = (const float*)d_in[2];
    const float* c0w = (const float*)d_in[3];
    const float* c0b = (const float*)d_in[4];
    const float* c1w = (const float*)d_in[5];
    const float* c1b = (const float*)d_in[6];
    const float* r1w = (const float*)d_in[7];
    const float* r3w = (const float*)d_in[8];
    const float* tw  = (const float*)d_in[9];
    float* out = (float*)d_out;
    float* ws  = (float*)d_ws;
    const size_t B = BATCH;

    // d_out layout: us0, f, a, diva0..diva4
    size_t off_us0 = 0;
    size_t off_f   = B * 16129;
    size_t off_a   = off_f + B * 16129;
    size_t off_d0  = off_a + B * 16384;
    size_t off_d1  = off_d0 + B * 16129;
    size_t off_d2  = off_d1 + B * 3969;
    size_t off_d3  = off_d2 + B * 961;
    size_t off_d4  = off_d3 + B * 225;

    // ws layout: a1, r1, us1, us2
    size_t w_a1  = 0;
    size_t w_r1  = w_a1 + B * 4096;
    size_t w_us1 = w_r1 + B * 3969;
    size_t w_us2 = w_us1 + B * 3969;

    dim3 blk(256);
    k_L01<<<dim3(16, B), blk, 0, stream>>>(
        u, f, a, c0w, c0b, c1w, c1b, r1w, r3w,
        out + off_us0, out + off_d0, out + off_f, out + off_a,
        out + off_d1, ws + w_a1, ws + w_r1, ws + w_us1);

    k_coarse<<<dim3(1024), blk, 0, stream>>>(
        ws + w_a1, ws + w_r1, r1w, r3w, c1w, c1b, c0w, c0b, tw,
        out + off_d2, out + off_d3, out + off_d4, ws + w_us2);

    k_prolong2<<<dim3(8, B), blk, 0, stream>>>(
        out + off_us0, ws + w_us1, ws + w_us2, tw);
}